// Round 3
// baseline (214.403 us; speedup 1.0000x reference)
//
#include <hip/hip_runtime.h>
#include <hip/hip_bf16.h>
#include <stdint.h>

typedef __attribute__((ext_vector_type(8))) short short8;
typedef __attribute__((ext_vector_type(4))) float floatx4;

using bf16 = __hip_bfloat16;

// QK_SCALE * LOG2E folded: scores arrive pre-scaled to log2 domain
#define SCALE_L2 0.12751793359133147f

__device__ inline unsigned short f2b(float f) {
    bf16 h = __float2bfloat16(f);
    return *(unsigned short*)&h;
}
__device__ inline float b2f(unsigned short u) {
    union { unsigned int i; float f; } v;
    v.i = ((unsigned int)u) << 16;
    return v.f;
}

// async global->LDS, 16B/lane; LDS dest = wave-uniform base + lane*16
__device__ __forceinline__ void gll16(const bf16* g, bf16* l) {
    __builtin_amdgcn_global_load_lds((__attribute__((address_space(1))) void*)g,
                                     (__attribute__((address_space(3))) void*)l,
                                     16, 0, 0);
}

// ---------------------------------------------------------------------------
// Fused prep: enc f32->bf16 (blocks 0..8191) + weight transposes (blocks 8192+)
// ---------------------------------------------------------------------------
__global__ __launch_bounds__(256) void prep_all(const float4* __restrict__ enc4,
                                                ushort4* __restrict__ encb4,
                                                const float* __restrict__ Wq,
                                                const float* __restrict__ Wk,
                                                const float* __restrict__ Wv,
                                                const float* __restrict__ Wo,
                                                bf16* __restrict__ Wqkvt,
                                                bf16* __restrict__ Wot) {
    int bx = blockIdx.x;
    if (bx < 8192) {
        int i = bx * 256 + threadIdx.x;  // 2,097,152 float4
        float4 v = enc4[i];
        ushort4 o;
        o.x = f2b(v.x); o.y = f2b(v.y); o.z = f2b(v.z); o.w = f2b(v.w);
        encb4[i] = o;
    } else {
        int idx = (bx - 8192) * 256 + threadIdx.x;  // 4 * 131072
        int sel = idx >> 17;
        int i = idx & 131071;
        if (sel < 3) {
            const float* W = (sel == 0) ? Wq : (sel == 1) ? Wk : Wv;
            int r = i >> 7, c = i & 127;  // src [1024][128]
            Wqkvt[(size_t)(sel * 128 + c) * 1024 + r] = __float2bfloat16(W[i]);
        } else {
            int r = i >> 10, c = i & 1023;  // src [128][1024]
            Wot[(size_t)c * 128 + r] = __float2bfloat16(Wo[i]);
        }
    }
}

// ---------------------------------------------------------------------------
// QKV GEMM, m97-style: 64x128 tiles, BK=32, grid (128,3).
// Staging via global_load_lds width-16 into unpadded lane-ordered LDS [r][32].
// 4 waves 2x2 (wave = 32x64, acc[2][4], 8 MFMA/k-iter).
// ---------------------------------------------------------------------------
__global__ __launch_bounds__(256) void gemm_qkv(const bf16* __restrict__ A,
                                                const bf16* __restrict__ Bt,
                                                bf16* __restrict__ Qb,
                                                bf16* __restrict__ Kb,
                                                bf16* __restrict__ Vtb) {
    __shared__ bf16 As[64 * 32];    // unpadded: gll lane-order = [r][32]
    __shared__ bf16 Bs[128 * 32];

    const int tid = threadIdx.x;
    const int m0 = blockIdx.x * 64;
    const int nsel = blockIdx.y;          // 0=Q 1=K 2=V
    const int brow0 = nsel * 128;
    const int w = tid >> 6, lane = tid & 63;
    const int wm = (w >> 1) * 32, wn = (w & 1) * 64;
    const int quad = lane >> 4, l16 = lane & 15;

    // staging: lane t covers LDS elems [t*8, t*8+8) => row t>>2, kcol (t&3)*8
    const int ar = tid >> 2, akq = (tid & 3) * 8;
    const int br1 = (tid + 256) >> 2;
    bf16* As_w  = &As[w * 512];           // wave-uniform LDS bases
    bf16* Bs_w0 = &Bs[w * 512];
    bf16* Bs_w1 = &Bs[2048 + w * 512];

    floatx4 acc[2][4];
#pragma unroll
    for (int i = 0; i < 2; i++)
#pragma unroll
        for (int j = 0; j < 4; j++) acc[i][j] = (floatx4){0.f, 0.f, 0.f, 0.f};

    for (int k0 = 0; k0 < 1024; k0 += 32) {
        __syncthreads();  // protect LDS reuse
        gll16(&A[(size_t)(m0 + ar) * 1024 + k0 + akq], As_w);
        gll16(&Bt[(size_t)(brow0 + ar) * 1024 + k0 + akq], Bs_w0);
        gll16(&Bt[(size_t)(brow0 + br1) * 1024 + k0 + akq], Bs_w1);
        __syncthreads();  // vmcnt(0) drain -> LDS filled

        short8 a[2], b[4];
#pragma unroll
        for (int mt = 0; mt < 2; mt++)
            a[mt] = *(const short8*)&As[(wm + mt * 16 + l16) * 32 + quad * 8];
#pragma unroll
        for (int nt = 0; nt < 4; nt++)
            b[nt] = *(const short8*)&Bs[(wn + nt * 16 + l16) * 32 + quad * 8];
#pragma unroll
        for (int mt = 0; mt < 2; mt++)
#pragma unroll
            for (int nt = 0; nt < 4; nt++)
                acc[mt][nt] = __builtin_amdgcn_mfma_f32_16x16x32_bf16(a[mt], b[nt], acc[mt][nt], 0, 0, 0);
    }

#pragma unroll
    for (int mt = 0; mt < 2; mt++)
#pragma unroll
        for (int nt = 0; nt < 4; nt++)
#pragma unroll
            for (int r = 0; r < 4; r++) {
                int row = m0 + wm + mt * 16 + quad * 4 + r;
                int col = wn + nt * 16 + l16;  // 0..127 within projection
                bf16 h = __float2bfloat16(acc[mt][nt][r]);
                if (nsel == 0) {
                    Qb[(size_t)row * 128 + col] = h;
                } else if (nsel == 1) {
                    Kb[(size_t)row * 128 + col] = h;
                } else {
                    int bb = row >> 11, ss = row & 2047;
                    Vtb[(size_t)bb * 262144 + (size_t)col * 2048 + ss] = h;
                }
            }
}

// ---------------------------------------------------------------------------
// Out-proj GEMM: C[8192,1024] = Sc[8192,128] * Wot[1024,128]^T, f32 out.
// 64x128 tiles, grid (128, 8). Register prefetch.
// ---------------------------------------------------------------------------
__global__ __launch_bounds__(256) void gemm_out(const bf16* __restrict__ A,
                                                const bf16* __restrict__ Bt,
                                                float* __restrict__ C) {
    __shared__ bf16 As[64 * 40];
    __shared__ bf16 Bs[128 * 40];

    const int tid = threadIdx.x;
    const int m0 = blockIdx.x * 64;
    const int n0 = blockIdx.y * 128;
    const int w = tid >> 6, lane = tid & 63;
    const int wm = (w >> 1) * 32, wn = (w & 1) * 64;
    const int quad = lane >> 4, l16 = lane & 15;

    const int ra = tid >> 2, ca = (tid & 3) * 8;
    const int rb0 = tid >> 2, rb1 = (tid + 256) >> 2;

    floatx4 acc[2][4];
#pragma unroll
    for (int i = 0; i < 2; i++)
#pragma unroll
        for (int j = 0; j < 4; j++) acc[i][j] = (floatx4){0.f, 0.f, 0.f, 0.f};

    int4 pa  = *(const int4*)&A[(size_t)(m0 + ra) * 128 + ca];
    int4 pb0 = *(const int4*)&Bt[(size_t)(n0 + rb0) * 128 + ca];
    int4 pb1 = *(const int4*)&Bt[(size_t)(n0 + rb1) * 128 + ca];

    for (int k0 = 0; k0 < 128; k0 += 32) {
        __syncthreads();
        *(int4*)&As[ra * 40 + ca] = pa;
        *(int4*)&Bs[rb0 * 40 + ca] = pb0;
        *(int4*)&Bs[rb1 * 40 + ca] = pb1;
        __syncthreads();

        if (k0 + 32 < 128) {
            pa  = *(const int4*)&A[(size_t)(m0 + ra) * 128 + k0 + 32 + ca];
            pb0 = *(const int4*)&Bt[(size_t)(n0 + rb0) * 128 + k0 + 32 + ca];
            pb1 = *(const int4*)&Bt[(size_t)(n0 + rb1) * 128 + k0 + 32 + ca];
        }

        short8 a[2], b[4];
#pragma unroll
        for (int mt = 0; mt < 2; mt++)
            a[mt] = *(const short8*)&As[(wm + mt * 16 + l16) * 40 + quad * 8];
#pragma unroll
        for (int nt = 0; nt < 4; nt++)
            b[nt] = *(const short8*)&Bs[(wn + nt * 16 + l16) * 40 + quad * 8];
#pragma unroll
        for (int mt = 0; mt < 2; mt++)
#pragma unroll
            for (int nt = 0; nt < 4; nt++)
                acc[mt][nt] = __builtin_amdgcn_mfma_f32_16x16x32_bf16(a[mt], b[nt], acc[mt][nt], 0, 0, 0);
    }

#pragma unroll
    for (int mt = 0; mt < 2; mt++)
#pragma unroll
        for (int nt = 0; nt < 4; nt++)
#pragma unroll
            for (int r = 0; r < 4; r++) {
                int row = m0 + wm + mt * 16 + quad * 4 + r;
                int col = n0 + wn + nt * 16 + l16;
                C[(size_t)row * 1024 + col] = acc[mt][nt][r];
            }
}

// ---------------------------------------------------------------------------
// Flash attention v7: SOFTWARE-PIPELINED, FAT-REGISTER. R2 post-mortem:
// three structures all ~46-48us; wall tracks total tile-iters/CU at ~13K
// cycles each. VGPR_Count=84 means the compiler streams K/V loads in small
// batches with a vmcnt wait each -> ~8 exposed L2/HBM latencies per tile.
// Fix: __launch_bounds__(256,1) frees the allocator (~200 VGPR), and the
// loop is an explicit pipeline with full-batch loads:
//   prologue: kc[16] <- K(start)
//   per tile: issue vc[16] <- V(kt)      (independent, flies under QK)
//             QK MFMAs on kc             (counted wait, vc outstanding)
//             issue kc[16] <- K(kt+1)    (kc dead after QK; flies under rest)
//             softmax (no memory)
//             P strip LDS RAW
//             PV MFMAs on vc             (counted wait, kc outstanding)
// Every wait is counted, never vmcnt(0). ILP replaces TLP.
// ---------------------------------------------------------------------------
__global__ __launch_bounds__(256, 1) void flash_split(const bf16* __restrict__ Q,
                                                      const bf16* __restrict__ K,
                                                      const bf16* __restrict__ Vt,
                                                      bf16* __restrict__ Opb,
                                                      float2* __restrict__ Ml) {
    // per-wave strip: 16x72 P (softmax phase, stride 72) then 16x136 obuf
    // (epilogue, stride 136). 4 waves * 2176 elems * 2B = 17408 B LDS.
    __shared__ bf16 Pw[4 * 2176];

    const int tid = threadIdx.x;
    const int x = blockIdx.x;          // global chunk id, [0, 1088)
    const int b = x / 272;
    const int id = x - b * 272;
    // invert C(qt) = floor((qt+1)^2/4): qt = largest with C(qt) <= id
    int qt = (int)__builtin_amdgcn_sqrtf(4.0f * (float)id + 1.0f) - 1;
    if (qt < 0) qt = 0;
    while (((qt + 2) * (qt + 2)) / 4 <= id) qt++;
    while (((qt + 1) * (qt + 1)) / 4 > id) qt--;
    const int c = id - ((qt + 1) * (qt + 1)) / 4;
    const int q0 = qt * 64;
    const int start = 2 * c;
    const int end = min(start + 2, qt + 1);

    const int w = tid >> 6, lane = tid & 63;
    const int quad = lane >> 4, l16 = lane & 15;
    bf16* myP = &Pw[w * 2176];

    // Q B-frag direct from global: lane l16 -> qrow, k = quad*8+j
    const int qrow = q0 + w * 16 + l16;
    const bf16* Qrow = &Q[((size_t)b * 2048 + qrow) * 128];
    short8 qf[4];
#pragma unroll
    for (int k4 = 0; k4 < 4; k4++)
        qf[k4] = *(const short8*)&Qrow[k4 * 32 + quad * 8];

    // per-lane fragment base pointers (A-operand layouts)
    // K frag(kt,nt,k4) = K[b][kt*64 + nt*16 + l16][k4*32 + quad*8 .. +8)
    const bf16* Kl = &K[((size_t)b * 2048 + l16) * 128 + quad * 8];
    // V frag(kt,d,k2) = Vt[b][d*16 + l16][kt*64 + k2*32 + quad*8 .. +8)
    const bf16* Vl = &Vt[(size_t)b * 262144 + (size_t)l16 * 2048 + quad * 8];

    float m_run = -1.0e30f, l_run = 0.f;  // per-lane q-row stats (log2 domain)
    floatx4 o[8];                         // O^T: col qrow=l16, rows d
#pragma unroll
    for (int d = 0; d < 8; d++) o[d] = (floatx4){0.f, 0.f, 0.f, 0.f};

    short8 kc[16], vc[16];
    // prologue: full K tile of first iteration in one batch
#pragma unroll
    for (int nt = 0; nt < 4; nt++)
#pragma unroll
        for (int k4 = 0; k4 < 4; k4++)
            kc[nt * 4 + k4] = *(const short8*)&Kl[(size_t)(start * 64 + nt * 16) * 128 + k4 * 32];

    for (int kt = start; kt < end; kt++) {
        // issue all 16 V frags for THIS tile (independent of kc; flies under QK)
#pragma unroll
        for (int d = 0; d < 8; d++)
#pragma unroll
            for (int k2 = 0; k2 < 2; k2++)
                vc[d * 2 + k2] = *(const short8*)&Vl[(size_t)(d * 16) * 2048 + kt * 64 + k2 * 32];

        // S^T = K * Q^T : A = K rows (kcols), B = qf. D col = qrow (l16)
        floatx4 s_acc[4];
#pragma unroll
        for (int nt = 0; nt < 4; nt++) {
            s_acc[nt] = (floatx4){0.f, 0.f, 0.f, 0.f};
#pragma unroll
            for (int k4 = 0; k4 < 4; k4++)
                s_acc[nt] = __builtin_amdgcn_mfma_f32_16x16x32_bf16(kc[nt * 4 + k4], qf[k4], s_acc[nt], 0, 0, 0);
        }

        // kc dead: prefetch next tile's K (flies under softmax + PV)
        if (kt + 1 < end) {
#pragma unroll
            for (int nt = 0; nt < 4; nt++)
#pragma unroll
                for (int k4 = 0; k4 < 4; k4++)
                    kc[nt * 4 + k4] = *(const short8*)&Kl[(size_t)((kt + 1) * 64 + nt * 16) * 128 + k4 * 32];
        }

        // per-lane 16 scores for q-row qrow, kcols kt*64 + nt*16 + quad*4 + r
        float sv[4][4];
#pragma unroll
        for (int nt = 0; nt < 4; nt++)
#pragma unroll
            for (int r = 0; r < 4; r++) {
                float s = s_acc[nt][r] * SCALE_L2;  // log2 domain
                if (kt == qt) {
                    int kcol = kt * 64 + nt * 16 + quad * 4 + r;
                    if (kcol > qrow) s = -1.0e9f;
                }
                sv[nt][r] = s;
            }

        float t0 = fmaxf(fmaxf(sv[0][0], sv[0][1]), fmaxf(sv[0][2], sv[0][3]));
        float t1 = fmaxf(fmaxf(sv[1][0], sv[1][1]), fmaxf(sv[1][2], sv[1][3]));
        float t2 = fmaxf(fmaxf(sv[2][0], sv[2][1]), fmaxf(sv[2][2], sv[2][3]));
        float t3 = fmaxf(fmaxf(sv[3][0], sv[3][1]), fmaxf(sv[3][2], sv[3][3]));
        float tmax = fmaxf(fmaxf(t0, t1), fmaxf(t2, t3));
        tmax = fmaxf(tmax, __shfl_xor(tmax, 16));
        tmax = fmaxf(tmax, __shfl_xor(tmax, 32));

        float mnew = fmaxf(m_run, tmax);
        float alpha = exp2f(m_run - mnew);
        m_run = mnew;

        float rsum = 0.f;
#pragma unroll
        for (int nt = 0; nt < 4; nt++)
#pragma unroll
            for (int r = 0; r < 4; r++) {
                float p = exp2f(sv[nt][r] - mnew);
                sv[nt][r] = p;
                rsum += p;
            }
        rsum += __shfl_xor(rsum, 16);
        rsum += __shfl_xor(rsum, 32);
        l_run = l_run * alpha + rsum;

        // P strip (per-wave, same-wave RAW, stride 72): myP[l16=qrow][kcol 0..63]
#pragma unroll
        for (int nt = 0; nt < 4; nt++) {
            ushort4 pk;
            pk.x = f2b(sv[nt][0]); pk.y = f2b(sv[nt][1]);
            pk.z = f2b(sv[nt][2]); pk.w = f2b(sv[nt][3]);
            *(ushort4*)&myP[l16 * 72 + nt * 16 + quad * 4] = pk;
        }

#pragma unroll
        for (int d = 0; d < 8; d++) {
            o[d][0] *= alpha; o[d][1] *= alpha; o[d][2] *= alpha; o[d][3] *= alpha;
        }

        // O^T += V^T * P^T : A = vc (prefetched), B = P strip
        short8 pf[2];
#pragma unroll
        for (int k2 = 0; k2 < 2; k2++)
            pf[k2] = *(const short8*)&myP[l16 * 72 + k2 * 32 + quad * 8];
#pragma unroll
        for (int d = 0; d < 8; d++)
#pragma unroll
            for (int k2 = 0; k2 < 2; k2++)
                o[d] = __builtin_amdgcn_mfma_f32_16x16x32_bf16(vc[d * 2 + k2], pf[k2], o[d], 0, 0, 0);
    }

    // epilogue: stage O^T tile through per-wave LDS (stride 136), then write
    // full-line coalesced: each store instr = 16 rows x 64B contiguous.
#pragma unroll
    for (int d = 0; d < 8; d++) {
        ushort4 pk;
        pk.x = f2b(o[d][0]); pk.y = f2b(o[d][1]);
        pk.z = f2b(o[d][2]); pk.w = f2b(o[d][3]);
        *(ushort4*)&myP[l16 * 136 + d * 16 + quad * 4] = pk;
    }
    const int er = lane >> 2;          // row 0..15 within wave tile
    const int ec = lane & 3;           // 16B chunk group
    const size_t orow = ((size_t)x * 64 + w * 16 + er) * 128;
#pragma unroll
    for (int p = 0; p < 4; p++) {
        int ce = (p * 4 + ec) * 8;     // element col 0..120
        short8 t = *(const short8*)&myP[er * 136 + ce];
        *(short8*)&Opb[orow + ce] = t;
    }
    if (lane < 16) Ml[(size_t)x * 64 + w * 16 + l16] = make_float2(m_run, l_run);
}

// ---------------------------------------------------------------------------
// Merge variable-count chunk partials -> normalized bf16 scores Sc[8192][128]
// Row (b,qt) has nc = qt/2+1 partials at ids b*272 + C(qt) .. +nc-1.
// Two-pass (max, then weighted sum) -> no register arrays (runtime-indexed
// arrays would spill to scratch).
// ---------------------------------------------------------------------------
__global__ __launch_bounds__(256) void flash_merge(const bf16* __restrict__ Opb,
                                                   const float2* __restrict__ Ml,
                                                   bf16* __restrict__ Sc) {
    int idx = blockIdx.x * 256 + threadIdx.x;  // 8192*32
    int row = idx >> 5, dg = (idx & 31) * 4;
    int b = row >> 11, s = row & 2047;
    int qt = s >> 6, rl = s & 63;
    int nc = (qt >> 1) + 1;
    int id0 = b * 272 + ((qt + 1) * (qt + 1)) / 4;

    float M = -1.0e30f;
    for (int j = 0; j < nc; j++)
        M = fmaxf(M, Ml[(size_t)(id0 + j) * 64 + rl].x);

    float L = 0.f;
    float a0 = 0.f, a1 = 0.f, a2 = 0.f, a3 = 0.f;
    for (int j = 0; j < nc; j++) {
        float2 t = Ml[(size_t)(id0 + j) * 64 + rl];
        float wj = exp2f(t.x - M);
        L += t.y * wj;
        ushort4 p = *(const ushort4*)&Opb[((size_t)(id0 + j) * 64 + rl) * 128 + dg];
        a0 += wj * b2f(p.x); a1 += wj * b2f(p.y);
        a2 += wj * b2f(p.z); a3 += wj * b2f(p.w);
    }
    float inv = 1.0f / L;
    ushort4 o;
    o.x = f2b(a0 * inv); o.y = f2b(a1 * inv);
    o.z = f2b(a2 * inv); o.w = f2b(a3 * inv);
    *(ushort4*)&Sc[(size_t)row * 128 + dg] = o;
}

// ---------------------------------------------------------------------------
extern "C" void kernel_launch(void* const* d_in, const int* in_sizes, int n_in,
                              void* d_out, int out_size, void* d_ws, size_t ws_size,
                              hipStream_t stream) {
    const float* enc = (const float*)d_in[0];
    // d_in[1] = mask: known causal triu(k=1); implemented analytically.
    const float* Wq = (const float*)d_in[2];
    const float* Wk = (const float*)d_in[3];
    const float* Wv = (const float*)d_in[4];
    const float* Wo = (const float*)d_in[5];
    float* out = (float*)d_out;

    const size_t MB = 1024 * 1024;
    char* ws = (char*)d_ws;
    // persistent buffers first, big transient region last:
    bf16*   Qb    = (bf16*)(ws);                          // 2 MB
    bf16*   Kb    = (bf16*)(ws + 2 * MB);                 // 2 MB
    bf16*   Vtb   = (bf16*)(ws + 4 * MB);                 // 2 MB  [B][128][2048]
    bf16*   Scb   = (bf16*)(ws + 6 * MB);                 // 2 MB
    bf16*   Wqkvt = (bf16*)(ws + 8 * MB);                 // 768 KB [384][1024]
    bf16*   Wot   = (bf16*)(ws + 8 * MB + 768 * 1024);    // 256 KB [1024][128]
    float2* Ml    = (float2*)(ws + 9 * MB);               // 557 KB [1088][64]
    bf16*   encb  = (bf16*)(ws + 10 * MB);                // 16 MB (dead after gemm_qkv)
    bf16*   Opb   = (bf16*)(ws + 10 * MB);                // 17.8 MB partials, alias encb

    prep_all<<<10240, 256, 0, stream>>>((const float4*)enc, (ushort4*)encb,
                                        Wq, Wk, Wv, Wo, Wqkvt, Wot);

    dim3 blk(256);
    gemm_qkv<<<dim3(128, 3), blk, 0, stream>>>(encb, Wqkvt, Qb, Kb, Vtb);

    flash_split<<<1088, blk, 0, stream>>>(Qb, Kb, Vtb, Opb, Ml);
    flash_merge<<<1024, blk, 0, stream>>>(Opb, Ml, Scb);

    gemm_out<<<dim3(128, 8), blk, 0, stream>>>(Scb, Wot, out);
}

// Round 4
// 204.059 us; speedup vs baseline: 1.0507x; 1.0507x over previous
//
#include <hip/hip_runtime.h>
#include <hip/hip_bf16.h>
#include <stdint.h>

typedef __attribute__((ext_vector_type(8))) short short8;
typedef __attribute__((ext_vector_type(4))) float floatx4;

using bf16 = __hip_bfloat16;

// QK_SCALE * LOG2E folded: scores arrive pre-scaled to log2 domain
#define SCALE_L2 0.12751793359133147f

__device__ inline unsigned short f2b(float f) {
    bf16 h = __float2bfloat16(f);
    return *(unsigned short*)&h;
}
__device__ inline float b2f(unsigned short u) {
    union { unsigned int i; float f; } v;
    v.i = ((unsigned int)u) << 16;
    return v.f;
}

// async global->LDS, 16B/lane; LDS dest = wave-uniform base + lane*16
__device__ __forceinline__ void gll16(const bf16* g, bf16* l) {
    __builtin_amdgcn_global_load_lds((__attribute__((address_space(1))) void*)g,
                                     (__attribute__((address_space(3))) void*)l,
                                     16, 0, 0);
}

// ---------------------------------------------------------------------------
// Fused prep: enc f32->bf16 (blocks 0..8191) + weight transposes (blocks 8192+)
// ---------------------------------------------------------------------------
__global__ __launch_bounds__(256) void prep_all(const float4* __restrict__ enc4,
                                                ushort4* __restrict__ encb4,
                                                const float* __restrict__ Wq,
                                                const float* __restrict__ Wk,
                                                const float* __restrict__ Wv,
                                                const float* __restrict__ Wo,
                                                bf16* __restrict__ Wqkvt,
                                                bf16* __restrict__ Wot) {
    int bx = blockIdx.x;
    if (bx < 8192) {
        int i = bx * 256 + threadIdx.x;  // 2,097,152 float4
        float4 v = enc4[i];
        ushort4 o;
        o.x = f2b(v.x); o.y = f2b(v.y); o.z = f2b(v.z); o.w = f2b(v.w);
        encb4[i] = o;
    } else {
        int idx = (bx - 8192) * 256 + threadIdx.x;  // 4 * 131072
        int sel = idx >> 17;
        int i = idx & 131071;
        if (sel < 3) {
            const float* W = (sel == 0) ? Wq : (sel == 1) ? Wk : Wv;
            int r = i >> 7, c = i & 127;  // src [1024][128]
            Wqkvt[(size_t)(sel * 128 + c) * 1024 + r] = __float2bfloat16(W[i]);
        } else {
            int r = i >> 10, c = i & 1023;  // src [128][1024]
            Wot[(size_t)c * 128 + r] = __float2bfloat16(Wo[i]);
        }
    }
}

// ---------------------------------------------------------------------------
// QKV GEMM v2: 64x64 tiles, BK=32, grid (128,6) = 768 blocks = exactly
// 3 blocks/CU (v1 was 384 blocks = 1.5/CU -> half the CUs ran 2 serial
// blocks). 4 waves 2x2 (wave = 32x32, acc[2][2], 4 MFMA/k-iter).
// Staging via global_load_lds width-16, unpadded lane-ordered LDS [r][32].
// ---------------------------------------------------------------------------
__global__ __launch_bounds__(256) void gemm_qkv(const bf16* __restrict__ A,
                                                const bf16* __restrict__ Bt,
                                                bf16* __restrict__ Qb,
                                                bf16* __restrict__ Kb,
                                                bf16* __restrict__ Vtb) {
    __shared__ bf16 As[64 * 32];    // unpadded: gll lane-order = [r][32]
    __shared__ bf16 Bs[64 * 32];

    const int tid = threadIdx.x;
    const int m0 = blockIdx.x * 64;
    const int by = blockIdx.y;            // 0..5
    const int nsel = by >> 1;             // 0=Q 1=K 2=V
    const int nh = by & 1;                // column half within projection
    const int brow0 = nsel * 128 + nh * 64;
    const int w = tid >> 6, lane = tid & 63;
    const int wm = (w >> 1) * 32, wn = (w & 1) * 32;
    const int quad = lane >> 4, l16 = lane & 15;

    // staging: lane t covers LDS elems [t*8, t*8+8) => row t>>2, kcol (t&3)*8
    const int ar = tid >> 2, akq = (tid & 3) * 8;
    bf16* As_w = &As[w * 512];            // wave-uniform LDS bases
    bf16* Bs_w = &Bs[w * 512];

    floatx4 acc[2][2];
#pragma unroll
    for (int i = 0; i < 2; i++)
#pragma unroll
        for (int j = 0; j < 2; j++) acc[i][j] = (floatx4){0.f, 0.f, 0.f, 0.f};

    for (int k0 = 0; k0 < 1024; k0 += 32) {
        __syncthreads();  // protect LDS reuse
        gll16(&A[(size_t)(m0 + ar) * 1024 + k0 + akq], As_w);
        gll16(&Bt[(size_t)(brow0 + ar) * 1024 + k0 + akq], Bs_w);
        __syncthreads();  // vmcnt(0) drain -> LDS filled

        short8 a[2], b[2];
#pragma unroll
        for (int mt = 0; mt < 2; mt++)
            a[mt] = *(const short8*)&As[(wm + mt * 16 + l16) * 32 + quad * 8];
#pragma unroll
        for (int nt = 0; nt < 2; nt++)
            b[nt] = *(const short8*)&Bs[(wn + nt * 16 + l16) * 32 + quad * 8];
#pragma unroll
        for (int mt = 0; mt < 2; mt++)
#pragma unroll
            for (int nt = 0; nt < 2; nt++)
                acc[mt][nt] = __builtin_amdgcn_mfma_f32_16x16x32_bf16(a[mt], b[nt], acc[mt][nt], 0, 0, 0);
    }

#pragma unroll
    for (int mt = 0; mt < 2; mt++)
#pragma unroll
        for (int nt = 0; nt < 2; nt++)
#pragma unroll
            for (int r = 0; r < 4; r++) {
                int row = m0 + wm + mt * 16 + quad * 4 + r;
                int col = nh * 64 + wn + nt * 16 + l16;  // 0..127 within projection
                bf16 h = __float2bfloat16(acc[mt][nt][r]);
                if (nsel == 0) {
                    Qb[(size_t)row * 128 + col] = h;
                } else if (nsel == 1) {
                    Kb[(size_t)row * 128 + col] = h;
                } else {
                    int bb = row >> 11, ss = row & 2047;
                    Vtb[(size_t)bb * 262144 + (size_t)col * 2048 + ss] = h;
                }
            }
}

// ---------------------------------------------------------------------------
// Out-proj GEMM: C[8192,1024] = Sc[8192,128] * Wot[1024,128]^T, f32 out.
// 64x128 tiles, grid (128, 8). Register prefetch.
// ---------------------------------------------------------------------------
__global__ __launch_bounds__(256) void gemm_out(const bf16* __restrict__ A,
                                                const bf16* __restrict__ Bt,
                                                float* __restrict__ C) {
    __shared__ bf16 As[64 * 40];
    __shared__ bf16 Bs[128 * 40];

    const int tid = threadIdx.x;
    const int m0 = blockIdx.x * 64;
    const int n0 = blockIdx.y * 128;
    const int w = tid >> 6, lane = tid & 63;
    const int wm = (w >> 1) * 32, wn = (w & 1) * 64;
    const int quad = lane >> 4, l16 = lane & 15;

    const int ra = tid >> 2, ca = (tid & 3) * 8;
    const int rb0 = tid >> 2, rb1 = (tid + 256) >> 2;

    floatx4 acc[2][4];
#pragma unroll
    for (int i = 0; i < 2; i++)
#pragma unroll
        for (int j = 0; j < 4; j++) acc[i][j] = (floatx4){0.f, 0.f, 0.f, 0.f};

    int4 pa  = *(const int4*)&A[(size_t)(m0 + ra) * 128 + ca];
    int4 pb0 = *(const int4*)&Bt[(size_t)(n0 + rb0) * 128 + ca];
    int4 pb1 = *(const int4*)&Bt[(size_t)(n0 + rb1) * 128 + ca];

    for (int k0 = 0; k0 < 128; k0 += 32) {
        __syncthreads();
        *(int4*)&As[ra * 40 + ca] = pa;
        *(int4*)&Bs[rb0 * 40 + ca] = pb0;
        *(int4*)&Bs[rb1 * 40 + ca] = pb1;
        __syncthreads();

        if (k0 + 32 < 128) {
            pa  = *(const int4*)&A[(size_t)(m0 + ra) * 128 + k0 + 32 + ca];
            pb0 = *(const int4*)&Bt[(size_t)(n0 + rb0) * 128 + k0 + 32 + ca];
            pb1 = *(const int4*)&Bt[(size_t)(n0 + rb1) * 128 + k0 + 32 + ca];
        }

        short8 a[2], b[4];
#pragma unroll
        for (int mt = 0; mt < 2; mt++)
            a[mt] = *(const short8*)&As[(wm + mt * 16 + l16) * 40 + quad * 8];
#pragma unroll
        for (int nt = 0; nt < 4; nt++)
            b[nt] = *(const short8*)&Bs[(wn + nt * 16 + l16) * 40 + quad * 8];
#pragma unroll
        for (int mt = 0; mt < 2; mt++)
#pragma unroll
            for (int nt = 0; nt < 4; nt++)
                acc[mt][nt] = __builtin_amdgcn_mfma_f32_16x16x32_bf16(a[mt], b[nt], acc[mt][nt], 0, 0, 0);
    }

#pragma unroll
    for (int mt = 0; mt < 2; mt++)
#pragma unroll
        for (int nt = 0; nt < 4; nt++)
#pragma unroll
            for (int r = 0; r < 4; r++) {
                int row = m0 + wm + mt * 16 + quad * 4 + r;
                int col = n0 + wn + nt * 16 + l16;
                C[(size_t)row * 1024 + col] = acc[mt][nt][r];
            }
}

// ---------------------------------------------------------------------------
// Flash attention v8: ONE-WAVE BLOCKS (max TLP probe). R3 showed duration is
// invariant to barriers, chain length, occupancy-vs-ILP tradeoff — all runs
// sampled only 2.5-6.4 resident waves/CU. v8 pushes the TLP axis hard: each
// 64-thread block = one wave handling 16 q-rows x <=2 k-tiles. 4352 fully
// independent blocks (~17/CU), VGPR-light v6 body (no fat pipeline).
// A/B outcome: big drop => latency/TLP theory; unchanged => per-CU shared
// resource (L1 VMEM throughput) => next round stages K/V in shared LDS.
// ---------------------------------------------------------------------------
__global__ __launch_bounds__(64) void flash_split(const bf16* __restrict__ Q,
                                                  const bf16* __restrict__ K,
                                                  const bf16* __restrict__ Vt,
                                                  bf16* __restrict__ Opb,
                                                  float2* __restrict__ Ml) {
    // single-wave strip: 16x72 P (softmax phase, stride 72) then 16x136 obuf
    // (epilogue, stride 136). 2176 elems * 2B = 4352 B LDS.
    __shared__ bf16 Pw[2176];

    const int tid = threadIdx.x;
    const int x = blockIdx.x;          // [0, 4352)
    const int b = x / 1088;
    const int rr = x - b * 1088;
    const int id = rr >> 2;            // chunk id within batch [0,272)
    const int strip = rr & 3;          // 16-row q-strip within the 64-row tile
    // invert C(qt) = floor((qt+1)^2/4): qt = largest with C(qt) <= id
    int qt = (int)__builtin_amdgcn_sqrtf(4.0f * (float)id + 1.0f) - 1;
    if (qt < 0) qt = 0;
    while (((qt + 2) * (qt + 2)) / 4 <= id) qt++;
    while (((qt + 1) * (qt + 1)) / 4 > id) qt--;
    const int c = id - ((qt + 1) * (qt + 1)) / 4;
    const int q0 = qt * 64;
    const int start = 2 * c;
    const int end = min(start + 2, qt + 1);

    const int lane = tid;
    const int quad = lane >> 4, l16 = lane & 15;
    bf16* myP = Pw;

    // Q B-frag direct from global: lane l16 -> qrow, k = quad*8+j
    const int qrow = q0 + strip * 16 + l16;
    const bf16* Qrow = &Q[((size_t)b * 2048 + qrow) * 128];
    short8 qf[4];
#pragma unroll
    for (int k4 = 0; k4 < 4; k4++)
        qf[k4] = *(const short8*)&Qrow[k4 * 32 + quad * 8];

    // per-lane fragment base pointers (A-operand layouts)
    // K frag(kt,nt,k4) = K[b][kt*64 + nt*16 + l16][k4*32 + quad*8 .. +8)
    const bf16* Kl = &K[((size_t)b * 2048 + l16) * 128 + quad * 8];
    // V frag(kt,d,k2) = Vt[b][d*16 + l16][kt*64 + k2*32 + quad*8 .. +8)
    const bf16* Vl = &Vt[(size_t)b * 262144 + (size_t)l16 * 2048 + quad * 8];

    float m_run = -1.0e30f, l_run = 0.f;  // per-lane q-row stats (log2 domain)
    floatx4 o[8];                         // O^T: col qrow=l16, rows d
#pragma unroll
    for (int d = 0; d < 8; d++) o[d] = (floatx4){0.f, 0.f, 0.f, 0.f};

    for (int kt = start; kt < end; kt++) {
        // K tile fragments -> 16 regs (16 independent dwordx4 loads, L2-served)
        short8 kc[16];
#pragma unroll
        for (int nt = 0; nt < 4; nt++)
#pragma unroll
            for (int k4 = 0; k4 < 4; k4++)
                kc[nt * 4 + k4] = *(const short8*)&Kl[(size_t)(kt * 64 + nt * 16) * 128 + k4 * 32];

        // S^T = K * Q^T : A = K rows (kcols), B = qf. D col = qrow (l16)
        floatx4 s_acc[4];
#pragma unroll
        for (int nt = 0; nt < 4; nt++) {
            s_acc[nt] = (floatx4){0.f, 0.f, 0.f, 0.f};
#pragma unroll
            for (int k4 = 0; k4 < 4; k4++)
                s_acc[nt] = __builtin_amdgcn_mfma_f32_16x16x32_bf16(kc[nt * 4 + k4], qf[k4], s_acc[nt], 0, 0, 0);
        }

        // per-lane 16 scores for q-row qrow, kcols kt*64 + nt*16 + quad*4 + r
        float sv[4][4];
#pragma unroll
        for (int nt = 0; nt < 4; nt++)
#pragma unroll
            for (int r = 0; r < 4; r++) {
                float s = s_acc[nt][r] * SCALE_L2;  // log2 domain
                if (kt == qt) {
                    int kcol = kt * 64 + nt * 16 + quad * 4 + r;
                    if (kcol > qrow) s = -1.0e9f;
                }
                sv[nt][r] = s;
            }

        float t0 = fmaxf(fmaxf(sv[0][0], sv[0][1]), fmaxf(sv[0][2], sv[0][3]));
        float t1 = fmaxf(fmaxf(sv[1][0], sv[1][1]), fmaxf(sv[1][2], sv[1][3]));
        float t2 = fmaxf(fmaxf(sv[2][0], sv[2][1]), fmaxf(sv[2][2], sv[2][3]));
        float t3 = fmaxf(fmaxf(sv[3][0], sv[3][1]), fmaxf(sv[3][2], sv[3][3]));
        float tmax = fmaxf(fmaxf(t0, t1), fmaxf(t2, t3));
        tmax = fmaxf(tmax, __shfl_xor(tmax, 16));
        tmax = fmaxf(tmax, __shfl_xor(tmax, 32));

        float mnew = fmaxf(m_run, tmax);
        float alpha = exp2f(m_run - mnew);
        m_run = mnew;

        float rsum = 0.f;
#pragma unroll
        for (int nt = 0; nt < 4; nt++)
#pragma unroll
            for (int r = 0; r < 4; r++) {
                float p = exp2f(sv[nt][r] - mnew);
                sv[nt][r] = p;
                rsum += p;
            }
        rsum += __shfl_xor(rsum, 16);
        rsum += __shfl_xor(rsum, 32);
        l_run = l_run * alpha + rsum;

        // P strip (same-wave RAW, stride 72): myP[l16=qrow][kcol 0..63]
#pragma unroll
        for (int nt = 0; nt < 4; nt++) {
            ushort4 pk;
            pk.x = f2b(sv[nt][0]); pk.y = f2b(sv[nt][1]);
            pk.z = f2b(sv[nt][2]); pk.w = f2b(sv[nt][3]);
            *(ushort4*)&myP[l16 * 72 + nt * 16 + quad * 4] = pk;
        }

#pragma unroll
        for (int d = 0; d < 8; d++) {
            o[d][0] *= alpha; o[d][1] *= alpha; o[d][2] *= alpha; o[d][3] *= alpha;
        }

        // O^T += V^T * P^T : A = V^T rows (d) direct from global, B = P strip
        short8 pf[2];
#pragma unroll
        for (int k2 = 0; k2 < 2; k2++)
            pf[k2] = *(const short8*)&myP[l16 * 72 + k2 * 32 + quad * 8];
#pragma unroll
        for (int d = 0; d < 8; d++)
#pragma unroll
            for (int k2 = 0; k2 < 2; k2++) {
                short8 vf = *(const short8*)&Vl[(size_t)(d * 16) * 2048 + kt * 64 + k2 * 32];
                o[d] = __builtin_amdgcn_mfma_f32_16x16x32_bf16(vf, pf[k2], o[d], 0, 0, 0);
            }
    }

    // epilogue: stage O^T tile through LDS (stride 136), then write
    // full-line coalesced: each store instr = 16 rows x 64B contiguous.
#pragma unroll
    for (int d = 0; d < 8; d++) {
        ushort4 pk;
        pk.x = f2b(o[d][0]); pk.y = f2b(o[d][1]);
        pk.z = f2b(o[d][2]); pk.w = f2b(o[d][3]);
        *(ushort4*)&myP[l16 * 136 + d * 16 + quad * 4] = pk;
    }
    const int chunk = b * 272 + id;
    const int er = lane >> 2;          // row 0..15 within strip
    const int ec = lane & 3;           // 16B chunk group
    const size_t orow = ((size_t)chunk * 64 + strip * 16 + er) * 128;
#pragma unroll
    for (int p = 0; p < 4; p++) {
        int ce = (p * 4 + ec) * 8;     // element col 0..120
        short8 t = *(const short8*)&myP[er * 136 + ce];
        *(short8*)&Opb[orow + ce] = t;
    }
    if (lane < 16) Ml[(size_t)chunk * 64 + strip * 16 + l16] = make_float2(m_run, l_run);
}

// ---------------------------------------------------------------------------
// Merge variable-count chunk partials -> normalized bf16 scores Sc[8192][128]
// Row (b,qt) has nc = qt/2+1 partials at ids b*272 + C(qt) .. +nc-1.
// Two-pass (max, then weighted sum) -> no register arrays (runtime-indexed
// arrays would spill to scratch).
// ---------------------------------------------------------------------------
__global__ __launch_bounds__(256) void flash_merge(const bf16* __restrict__ Opb,
                                                   const float2* __restrict__ Ml,
                                                   bf16* __restrict__ Sc) {
    int idx = blockIdx.x * 256 + threadIdx.x;  // 8192*32
    int row = idx >> 5, dg = (idx & 31) * 4;
    int b = row >> 11, s = row & 2047;
    int qt = s >> 6, rl = s & 63;
    int nc = (qt >> 1) + 1;
    int id0 = b * 272 + ((qt + 1) * (qt + 1)) / 4;

    float M = -1.0e30f;
    for (int j = 0; j < nc; j++)
        M = fmaxf(M, Ml[(size_t)(id0 + j) * 64 + rl].x);

    float L = 0.f;
    float a0 = 0.f, a1 = 0.f, a2 = 0.f, a3 = 0.f;
    for (int j = 0; j < nc; j++) {
        float2 t = Ml[(size_t)(id0 + j) * 64 + rl];
        float wj = exp2f(t.x - M);
        L += t.y * wj;
        ushort4 p = *(const ushort4*)&Opb[((size_t)(id0 + j) * 64 + rl) * 128 + dg];
        a0 += wj * b2f(p.x); a1 += wj * b2f(p.y);
        a2 += wj * b2f(p.z); a3 += wj * b2f(p.w);
    }
    float inv = 1.0f / L;
    ushort4 o;
    o.x = f2b(a0 * inv); o.y = f2b(a1 * inv);
    o.z = f2b(a2 * inv); o.w = f2b(a3 * inv);
    *(ushort4*)&Sc[(size_t)row * 128 + dg] = o;
}

// ---------------------------------------------------------------------------
extern "C" void kernel_launch(void* const* d_in, const int* in_sizes, int n_in,
                              void* d_out, int out_size, void* d_ws, size_t ws_size,
                              hipStream_t stream) {
    const float* enc = (const float*)d_in[0];
    // d_in[1] = mask: known causal triu(k=1); implemented analytically.
    const float* Wq = (const float*)d_in[2];
    const float* Wk = (const float*)d_in[3];
    const float* Wv = (const float*)d_in[4];
    const float* Wo = (const float*)d_in[5];
    float* out = (float*)d_out;

    const size_t MB = 1024 * 1024;
    char* ws = (char*)d_ws;
    // persistent buffers first, big transient region last:
    bf16*   Qb    = (bf16*)(ws);                          // 2 MB
    bf16*   Kb    = (bf16*)(ws + 2 * MB);                 // 2 MB
    bf16*   Vtb   = (bf16*)(ws + 4 * MB);                 // 2 MB  [B][128][2048]
    bf16*   Scb   = (bf16*)(ws + 6 * MB);                 // 2 MB
    bf16*   Wqkvt = (bf16*)(ws + 8 * MB);                 // 768 KB [384][1024]
    bf16*   Wot   = (bf16*)(ws + 8 * MB + 768 * 1024);    // 256 KB [1024][128]
    float2* Ml    = (float2*)(ws + 9 * MB);               // 557 KB [1088][64]
    bf16*   encb  = (bf16*)(ws + 10 * MB);                // 16 MB (dead after gemm_qkv)
    bf16*   Opb   = (bf16*)(ws + 10 * MB);                // 17.8 MB partials, alias encb

    prep_all<<<10240, 256, 0, stream>>>((const float4*)enc, (ushort4*)encb,
                                        Wq, Wk, Wv, Wo, Wqkvt, Wot);

    gemm_qkv<<<dim3(128, 6), dim3(256), 0, stream>>>(encb, Wqkvt, Qb, Kb, Vtb);

    flash_split<<<4352, dim3(64), 0, stream>>>(Qb, Kb, Vtb, Opb, Ml);
    flash_merge<<<1024, dim3(256), 0, stream>>>(Opb, Ml, Scb);

    gemm_out<<<dim3(128, 8), dim3(256), 0, stream>>>(Scb, Wot, out);
}

// Round 6
// 188.814 us; speedup vs baseline: 1.1355x; 1.0807x over previous
//
#include <hip/hip_runtime.h>
#include <hip/hip_bf16.h>
#include <stdint.h>

typedef __attribute__((ext_vector_type(8))) short short8;
typedef __attribute__((ext_vector_type(4))) float floatx4;

using bf16 = __hip_bfloat16;

// QK_SCALE * LOG2E folded: scores arrive pre-scaled to log2 domain
#define SCALE_L2 0.12751793359133147f

__device__ inline unsigned short f2b(float f) {
    bf16 h = __float2bfloat16(f);
    return *(unsigned short*)&h;
}
__device__ inline float b2f(unsigned short u) {
    union { unsigned int i; float f; } v;
    v.i = ((unsigned int)u) << 16;
    return v.f;
}

// async global->LDS, 16B/lane; LDS dest = wave-uniform base + lane*16
__device__ __forceinline__ void gll16(const bf16* g, bf16* l) {
    __builtin_amdgcn_global_load_lds((__attribute__((address_space(1))) void*)g,
                                     (__attribute__((address_space(3))) void*)l,
                                     16, 0, 0);
}

// ---------------------------------------------------------------------------
// Weight prep only (enc conversion fused into gemm_qkv): transposes
// Wq/Wk/Wv -> Wqkvt [384][1024] and Wo -> Wot [1024][128]. 524288 elems.
// ---------------------------------------------------------------------------
__global__ __launch_bounds__(256) void prep_w(const float* __restrict__ Wq,
                                              const float* __restrict__ Wk,
                                              const float* __restrict__ Wv,
                                              const float* __restrict__ Wo,
                                              bf16* __restrict__ Wqkvt,
                                              bf16* __restrict__ Wot) {
    int idx = blockIdx.x * 256 + threadIdx.x;  // 4 * 131072
    int sel = idx >> 17;
    int i = idx & 131071;
    if (sel < 3) {
        const float* W = (sel == 0) ? Wq : (sel == 1) ? Wk : Wv;
        int r = i >> 7, c = i & 127;  // src [1024][128]
        Wqkvt[(size_t)(sel * 128 + c) * 1024 + r] = __float2bfloat16(W[i]);
    } else {
        int r = i >> 10, c = i & 1023;  // src [128][1024]
        Wot[(size_t)c * 128 + r] = __float2bfloat16(Wo[i]);
    }
}

// ---------------------------------------------------------------------------
// QKV GEMM v3: reads enc f32 DIRECTLY (reg-staged f32->bf16 convert during
// A-staging) — the 48 MB prep enc pass is gone. 64x64 tiles, BK=32,
// grid (128,6) = 768 blocks = 3/CU. B via global_load_lds (bf16 Wqkvt).
// ---------------------------------------------------------------------------
__global__ __launch_bounds__(256) void gemm_qkv(const float* __restrict__ enc,
                                                const bf16* __restrict__ Bt,
                                                bf16* __restrict__ Qb,
                                                bf16* __restrict__ Kb,
                                                bf16* __restrict__ Vtb) {
    __shared__ __align__(16) bf16 As[64 * 32];
    __shared__ __align__(16) bf16 Bs[64 * 32];

    const int tid = threadIdx.x;
    const int m0 = blockIdx.x * 64;
    const int by = blockIdx.y;            // 0..5
    const int nsel = by >> 1;             // 0=Q 1=K 2=V
    const int nh = by & 1;                // column half within projection
    const int brow0 = nsel * 128 + nh * 64;
    const int w = tid >> 6, lane = tid & 63;
    const int wm = (w >> 1) * 32, wn = (w & 1) * 32;
    const int quad = lane >> 4, l16 = lane & 15;

    // staging: thread t covers As row t>>2, kcols (t&3)*8..+8
    const int ar = tid >> 2, akq = (tid & 3) * 8;
    bf16* Bs_w = &Bs[w * 512];            // wave-uniform LDS base

    const float4* Arow = (const float4*)&enc[(size_t)(m0 + ar) * 1024];
    const int af = (tid & 3) * 2;         // float4 index of this thread's 8 f32
    float4 a0 = Arow[af], a1 = Arow[af + 1];

    floatx4 acc[2][2];
#pragma unroll
    for (int i = 0; i < 2; i++)
#pragma unroll
        for (int j = 0; j < 2; j++) acc[i][j] = (floatx4){0.f, 0.f, 0.f, 0.f};

    for (int k0 = 0; k0 < 1024; k0 += 32) {
        __syncthreads();  // protect LDS reuse
        gll16(&Bt[(size_t)(brow0 + ar) * 1024 + k0 + akq], Bs_w);
        ushort4 u0, u1;
        u0.x = f2b(a0.x); u0.y = f2b(a0.y); u0.z = f2b(a0.z); u0.w = f2b(a0.w);
        u1.x = f2b(a1.x); u1.y = f2b(a1.y); u1.z = f2b(a1.z); u1.w = f2b(a1.w);
        *(ushort4*)&As[ar * 32 + akq] = u0;
        *(ushort4*)&As[ar * 32 + akq + 4] = u1;
        __syncthreads();  // drain vmcnt + lgkm -> LDS filled

        if (k0 + 32 < 1024) {             // register prefetch next A block
            a0 = Arow[((k0 + 32) >> 2) + af];
            a1 = Arow[((k0 + 32) >> 2) + af + 1];
        }

        short8 a[2], bfr[2];
#pragma unroll
        for (int mt = 0; mt < 2; mt++)
            a[mt] = *(const short8*)&As[(wm + mt * 16 + l16) * 32 + quad * 8];
#pragma unroll
        for (int nt = 0; nt < 2; nt++)
            bfr[nt] = *(const short8*)&Bs[(wn + nt * 16 + l16) * 32 + quad * 8];
#pragma unroll
        for (int mt = 0; mt < 2; mt++)
#pragma unroll
            for (int nt = 0; nt < 2; nt++)
                acc[mt][nt] = __builtin_amdgcn_mfma_f32_16x16x32_bf16(a[mt], bfr[nt], acc[mt][nt], 0, 0, 0);
    }

#pragma unroll
    for (int mt = 0; mt < 2; mt++)
#pragma unroll
        for (int nt = 0; nt < 2; nt++)
#pragma unroll
            for (int r = 0; r < 4; r++) {
                int row = m0 + wm + mt * 16 + quad * 4 + r;
                int col = nh * 64 + wn + nt * 16 + l16;  // 0..127 within projection
                bf16 h = __float2bfloat16(acc[mt][nt][r]);
                if (nsel == 0) {
                    Qb[(size_t)row * 128 + col] = h;
                } else if (nsel == 1) {
                    Kb[(size_t)row * 128 + col] = h;
                } else {
                    int bb = row >> 11, ss = row & 2047;
                    Vtb[(size_t)bb * 262144 + (size_t)col * 2048 + ss] = h;
                }
            }
}

// ---------------------------------------------------------------------------
// Out-proj GEMM: C[8192,1024] = Sc[8192,128] * Wot[1024,128]^T, f32 out.
// 64x128 tiles, grid (128, 8). Register prefetch.
// ---------------------------------------------------------------------------
__global__ __launch_bounds__(256) void gemm_out(const bf16* __restrict__ A,
                                                const bf16* __restrict__ Bt,
                                                float* __restrict__ C) {
    __shared__ bf16 As[64 * 40];
    __shared__ bf16 Bs[128 * 40];

    const int tid = threadIdx.x;
    const int m0 = blockIdx.x * 64;
    const int n0 = blockIdx.y * 128;
    const int w = tid >> 6, lane = tid & 63;
    const int wm = (w >> 1) * 32, wn = (w & 1) * 64;
    const int quad = lane >> 4, l16 = lane & 15;

    const int ra = tid >> 2, ca = (tid & 3) * 8;
    const int rb0 = tid >> 2, rb1 = (tid + 256) >> 2;

    floatx4 acc[2][4];
#pragma unroll
    for (int i = 0; i < 2; i++)
#pragma unroll
        for (int j = 0; j < 4; j++) acc[i][j] = (floatx4){0.f, 0.f, 0.f, 0.f};

    int4 pa  = *(const int4*)&A[(size_t)(m0 + ra) * 128 + ca];
    int4 pb0 = *(const int4*)&Bt[(size_t)(n0 + rb0) * 128 + ca];
    int4 pb1 = *(const int4*)&Bt[(size_t)(n0 + rb1) * 128 + ca];

    for (int k0 = 0; k0 < 128; k0 += 32) {
        __syncthreads();
        *(int4*)&As[ra * 40 + ca] = pa;
        *(int4*)&Bs[rb0 * 40 + ca] = pb0;
        *(int4*)&Bs[rb1 * 40 + ca] = pb1;
        __syncthreads();

        if (k0 + 32 < 128) {
            pa  = *(const int4*)&A[(size_t)(m0 + ra) * 128 + k0 + 32 + ca];
            pb0 = *(const int4*)&Bt[(size_t)(n0 + rb0) * 128 + k0 + 32 + ca];
            pb1 = *(const int4*)&Bt[(size_t)(n0 + rb1) * 128 + k0 + 32 + ca];
        }

        short8 a[2], b[4];
#pragma unroll
        for (int mt = 0; mt < 2; mt++)
            a[mt] = *(const short8*)&As[(wm + mt * 16 + l16) * 40 + quad * 8];
#pragma unroll
        for (int nt = 0; nt < 4; nt++)
            b[nt] = *(const short8*)&Bs[(wn + nt * 16 + l16) * 40 + quad * 8];
#pragma unroll
        for (int mt = 0; mt < 2; mt++)
#pragma unroll
            for (int nt = 0; nt < 4; nt++)
                acc[mt][nt] = __builtin_amdgcn_mfma_f32_16x16x32_bf16(a[mt], b[nt], acc[mt][nt], 0, 0, 0);
    }

#pragma unroll
    for (int mt = 0; mt < 2; mt++)
#pragma unroll
        for (int nt = 0; nt < 4; nt++)
#pragma unroll
            for (int r = 0; r < 4; r++) {
                int row = m0 + wm + mt * 16 + quad * 4 + r;
                int col = n0 + wn + nt * 16 + l16;
                C[(size_t)row * 1024 + col] = acc[mt][nt][r];
            }
}

// ---------------------------------------------------------------------------
// Flash attention v9: LDS-SHARED K/V. R4 showed residency is pinned (~6
// waves/CU regardless of grid shape) and every prior variant made each wave
// privately stream its K/V tiles (32 VMEM instr/wave-tile, 4x redundant per
// chunk, unhideable at low residency). v9 stages K [64][128] and V [128][64]
// ONCE per block via 8 global_load_lds issues (16x fewer VMEM instructions),
// shared by 4 waves. Row-major D=128 LDS is a 16-way bank conflict on
// ds_read_b128 -> XOR-swizzle byte ^= ((row&7)<<4), applied BOTH sides:
// pre-swizzled global source address (linear gll dest) + swizzled reads.
// Softmax / P-strip / PV math identical to v6.
// ---------------------------------------------------------------------------
__global__ __launch_bounds__(256) void flash_split(const bf16* __restrict__ Q,
                                                   const bf16* __restrict__ K,
                                                   const bf16* __restrict__ Vt,
                                                   bf16* __restrict__ Opb,
                                                   float2* __restrict__ Ml) {
    __shared__ __align__(16) bf16 Ks[64 * 128];   // 16 KB, swizzled
    __shared__ __align__(16) bf16 Vs[128 * 64];   // 16 KB, swizzled
    __shared__ __align__(16) bf16 Pw[4 * 2176];   // 17 KB per-wave strips

    const int tid = threadIdx.x;
    const int x = blockIdx.x;          // global chunk id, [0, 1088)
    const int b = x / 272;
    const int id = x - b * 272;
    // invert C(qt) = floor((qt+1)^2/4): qt = largest with C(qt) <= id
    int qt = (int)__builtin_amdgcn_sqrtf(4.0f * (float)id + 1.0f) - 1;
    if (qt < 0) qt = 0;
    while (((qt + 2) * (qt + 2)) / 4 <= id) qt++;
    while (((qt + 1) * (qt + 1)) / 4 > id) qt--;
    const int c = id - ((qt + 1) * (qt + 1)) / 4;
    const int q0 = qt * 64;
    const int start = 2 * c;
    const int end = min(start + 2, qt + 1);

    const int w = tid >> 6, lane = tid & 63;
    const int quad = lane >> 4, l16 = lane & 15;
    bf16* myP = &Pw[w * 2176];

    // staging geometry: issue i covers LDS bytes i*4096 + w*1024 + lane*16
    const int krow = w * 4 + (lane >> 4);   // + i*16 ; K row (256 B rows)
    const int kcb  = (lane & 15) * 16;      // byte col within K row
    const int vrow = w * 8 + (lane >> 3);   // + i*32 ; V row (128 B rows)
    const int vcb  = (lane & 7) * 16;       // byte col within V row
    const int ksw  = (l16 & 7) << 4;        // read-side XOR (row&7 == l16&7)

    // Q B-frag direct from global: lane l16 -> qrow, k = quad*8+j
    const int qrow = q0 + w * 16 + l16;
    const bf16* Qrow = &Q[((size_t)b * 2048 + qrow) * 128];
    short8 qf[4];
#pragma unroll
    for (int k4 = 0; k4 < 4; k4++)
        qf[k4] = *(const short8*)&Qrow[k4 * 32 + quad * 8];

    float m_run = -1.0e30f, l_run = 0.f;  // per-lane q-row stats (log2 domain)
    floatx4 o[8];                         // O^T: col qrow=l16, rows d
#pragma unroll
    for (int d = 0; d < 8; d++) o[d] = (floatx4){0.f, 0.f, 0.f, 0.f};

    // stage first tile (pre-swizzled global source, linear LDS dest)
    {
        const int kt = start;
#pragma unroll
        for (int i = 0; i < 4; i++) {
            int row = i * 16 + krow;
            int cbs = kcb ^ ((row & 7) << 4);
            gll16(&K[((size_t)b * 2048 + kt * 64 + row) * 128 + (cbs >> 1)],
                  &Ks[i * 2048 + w * 512]);
        }
#pragma unroll
        for (int i = 0; i < 4; i++) {
            int row = i * 32 + vrow;
            int cbs = vcb ^ ((row & 7) << 4);
            gll16(&Vt[(size_t)b * 262144 + (size_t)row * 2048 + kt * 64 + (cbs >> 1)],
                  &Vs[i * 2048 + w * 512]);
        }
    }
    __syncthreads();

    for (int kt = start; kt < end; kt++) {
        // S^T = K * Q^T : A = swizzled Ks rows (kcols), B = qf. D col = qrow
        floatx4 s_acc[4];
#pragma unroll
        for (int nt = 0; nt < 4; nt++) {
            s_acc[nt] = (floatx4){0.f, 0.f, 0.f, 0.f};
#pragma unroll
            for (int k4 = 0; k4 < 4; k4++) {
                short8 kf = *(const short8*)((const char*)Ks +
                              (nt * 16 + l16) * 256 + ((k4 * 64 + quad * 16) ^ ksw));
                s_acc[nt] = __builtin_amdgcn_mfma_f32_16x16x32_bf16(kf, qf[k4], s_acc[nt], 0, 0, 0);
            }
        }

        // per-lane 16 scores for q-row qrow, kcols kt*64 + nt*16 + quad*4 + r
        float sv[4][4];
#pragma unroll
        for (int nt = 0; nt < 4; nt++)
#pragma unroll
            for (int r = 0; r < 4; r++) {
                float s = s_acc[nt][r] * SCALE_L2;  // log2 domain
                if (kt == qt) {
                    int kcol = kt * 64 + nt * 16 + quad * 4 + r;
                    if (kcol > qrow) s = -1.0e9f;
                }
                sv[nt][r] = s;
            }

        float t0 = fmaxf(fmaxf(sv[0][0], sv[0][1]), fmaxf(sv[0][2], sv[0][3]));
        float t1 = fmaxf(fmaxf(sv[1][0], sv[1][1]), fmaxf(sv[1][2], sv[1][3]));
        float t2 = fmaxf(fmaxf(sv[2][0], sv[2][1]), fmaxf(sv[2][2], sv[2][3]));
        float t3 = fmaxf(fmaxf(sv[3][0], sv[3][1]), fmaxf(sv[3][2], sv[3][3]));
        float tmax = fmaxf(fmaxf(t0, t1), fmaxf(t2, t3));
        tmax = fmaxf(tmax, __shfl_xor(tmax, 16));
        tmax = fmaxf(tmax, __shfl_xor(tmax, 32));

        float mnew = fmaxf(m_run, tmax);
        float alpha = exp2f(m_run - mnew);
        m_run = mnew;

        float rsum = 0.f;
#pragma unroll
        for (int nt = 0; nt < 4; nt++)
#pragma unroll
            for (int r = 0; r < 4; r++) {
                float p = exp2f(sv[nt][r] - mnew);
                sv[nt][r] = p;
                rsum += p;
            }
        rsum += __shfl_xor(rsum, 16);
        rsum += __shfl_xor(rsum, 32);
        l_run = l_run * alpha + rsum;

        // P strip (per-wave, same-wave RAW, stride 72): myP[l16=qrow][kcol]
#pragma unroll
        for (int nt = 0; nt < 4; nt++) {
            ushort4 pk;
            pk.x = f2b(sv[nt][0]); pk.y = f2b(sv[nt][1]);
            pk.z = f2b(sv[nt][2]); pk.w = f2b(sv[nt][3]);
            *(ushort4*)&myP[l16 * 72 + nt * 16 + quad * 4] = pk;
        }

#pragma unroll
        for (int d = 0; d < 8; d++) {
            o[d][0] *= alpha; o[d][1] *= alpha; o[d][2] *= alpha; o[d][3] *= alpha;
        }

        // O^T += V^T * P^T : A = swizzled Vs rows (d), B = P strip
        short8 pf[2];
#pragma unroll
        for (int k2 = 0; k2 < 2; k2++)
            pf[k2] = *(const short8*)&myP[l16 * 72 + k2 * 32 + quad * 8];
#pragma unroll
        for (int d = 0; d < 8; d++)
#pragma unroll
            for (int k2 = 0; k2 < 2; k2++) {
                short8 vf = *(const short8*)((const char*)Vs +
                              (d * 16 + l16) * 128 + ((k2 * 64 + quad * 16) ^ ksw));
                o[d] = __builtin_amdgcn_mfma_f32_16x16x32_bf16(vf, pf[k2], o[d], 0, 0, 0);
            }

        // restage for next tile (all waves must be done reading Ks/Vs)
        if (kt + 1 < end) {
            __syncthreads();
            const int nk = kt + 1;
#pragma unroll
            for (int i = 0; i < 4; i++) {
                int row = i * 16 + krow;
                int cbs = kcb ^ ((row & 7) << 4);
                gll16(&K[((size_t)b * 2048 + nk * 64 + row) * 128 + (cbs >> 1)],
                      &Ks[i * 2048 + w * 512]);
            }
#pragma unroll
            for (int i = 0; i < 4; i++) {
                int row = i * 32 + vrow;
                int cbs = vcb ^ ((row & 7) << 4);
                gll16(&Vt[(size_t)b * 262144 + (size_t)row * 2048 + nk * 64 + (cbs >> 1)],
                      &Vs[i * 2048 + w * 512]);
            }
            __syncthreads();
        }
    }

    // epilogue: stage O^T tile through per-wave LDS (stride 136), then write
    // full-line coalesced: each store instr = 16 rows x 64B contiguous.
#pragma unroll
    for (int d = 0; d < 8; d++) {
        ushort4 pk;
        pk.x = f2b(o[d][0]); pk.y = f2b(o[d][1]);
        pk.z = f2b(o[d][2]); pk.w = f2b(o[d][3]);
        *(ushort4*)&myP[l16 * 136 + d * 16 + quad * 4] = pk;
    }
    const int er = lane >> 2;          // row 0..15 within wave tile
    const int ec = lane & 3;           // 16B chunk group
    const size_t orow = ((size_t)x * 64 + w * 16 + er) * 128;
#pragma unroll
    for (int p = 0; p < 4; p++) {
        int ce = (p * 4 + ec) * 8;     // element col 0..120
        short8 t = *(const short8*)&myP[er * 136 + ce];
        *(short8*)&Opb[orow + ce] = t;
    }
    if (lane < 16) Ml[(size_t)x * 64 + w * 16 + l16] = make_float2(m_run, l_run);
}

// ---------------------------------------------------------------------------
// Merge variable-count chunk partials -> normalized bf16 scores Sc[8192][128]
// Row (b,qt) has nc = qt/2+1 partials at ids b*272 + C(qt) .. +nc-1.
// Two-pass (max, then weighted sum) -> no register arrays.
// ---------------------------------------------------------------------------
__global__ __launch_bounds__(256) void flash_merge(const bf16* __restrict__ Opb,
                                                   const float2* __restrict__ Ml,
                                                   bf16* __restrict__ Sc) {
    int idx = blockIdx.x * 256 + threadIdx.x;  // 8192*32
    int row = idx >> 5, dg = (idx & 31) * 4;
    int b = row >> 11, s = row & 2047;
    int qt = s >> 6, rl = s & 63;
    int nc = (qt >> 1) + 1;
    int id0 = b * 272 + ((qt + 1) * (qt + 1)) / 4;

    float M = -1.0e30f;
    for (int j = 0; j < nc; j++)
        M = fmaxf(M, Ml[(size_t)(id0 + j) * 64 + rl].x);

    float L = 0.f;
    float a0 = 0.f, a1 = 0.f, a2 = 0.f, a3 = 0.f;
    for (int j = 0; j < nc; j++) {
        float2 t = Ml[(size_t)(id0 + j) * 64 + rl];
        float wj = exp2f(t.x - M);
        L += t.y * wj;
        ushort4 p = *(const ushort4*)&Opb[((size_t)(id0 + j) * 64 + rl) * 128 + dg];
        a0 += wj * b2f(p.x); a1 += wj * b2f(p.y);
        a2 += wj * b2f(p.z); a3 += wj * b2f(p.w);
    }
    float inv = 1.0f / L;
    ushort4 o;
    o.x = f2b(a0 * inv); o.y = f2b(a1 * inv);
    o.z = f2b(a2 * inv); o.w = f2b(a3 * inv);
    *(ushort4*)&Sc[(size_t)row * 128 + dg] = o;
}

// ---------------------------------------------------------------------------
extern "C" void kernel_launch(void* const* d_in, const int* in_sizes, int n_in,
                              void* d_out, int out_size, void* d_ws, size_t ws_size,
                              hipStream_t stream) {
    const float* enc = (const float*)d_in[0];
    // d_in[1] = mask: known causal triu(k=1); implemented analytically.
    const float* Wq = (const float*)d_in[2];
    const float* Wk = (const float*)d_in[3];
    const float* Wv = (const float*)d_in[4];
    const float* Wo = (const float*)d_in[5];
    float* out = (float*)d_out;

    const size_t MB = 1024 * 1024;
    char* ws = (char*)d_ws;
    bf16*   Qb    = (bf16*)(ws);                          // 2 MB
    bf16*   Kb    = (bf16*)(ws + 2 * MB);                 // 2 MB
    bf16*   Vtb   = (bf16*)(ws + 4 * MB);                 // 2 MB  [B][128][2048]
    bf16*   Scb   = (bf16*)(ws + 6 * MB);                 // 2 MB
    bf16*   Wqkvt = (bf16*)(ws + 8 * MB);                 // 768 KB [384][1024]
    bf16*   Wot   = (bf16*)(ws + 8 * MB + 768 * 1024);    // 256 KB [1024][128]
    float2* Ml    = (float2*)(ws + 9 * MB);               // 557 KB [1088][64]
    bf16*   Opb   = (bf16*)(ws + 10 * MB);                // 17.8 MB partials

    prep_w<<<2048, dim3(256), 0, stream>>>(Wq, Wk, Wv, Wo, Wqkvt, Wot);

    gemm_qkv<<<dim3(128, 6), dim3(256), 0, stream>>>(enc, Wqkvt, Qb, Kb, Vtb);

    flash_split<<<1088, dim3(256), 0, stream>>>(Qb, Kb, Vtb, Opb, Ml);
    flash_merge<<<1024, dim3(256), 0, stream>>>(Opb, Ml, Scb);

    gemm_out<<<dim3(128, 8), dim3(256), 0, stream>>>(Scb, Wot, out);
}